// Round 13
// baseline (589.901 us; speedup 1.0000x reference)
//
#include <hip/hip_runtime.h>
#include <hip/hip_bf16.h>
#include <stdint.h>

#define NROWS 8192      // B*L = 4*2048
#define BATCH 4
#define DM    1024
#define DI    2048
#define DSTATE 16
#define DTRANK 64
#define CL    32        // scan chunk length
#define SEGL  512       // scan segment length (S=4 segments)
#define NCH2  16        // SEGL / CL
#define CHTOT 131072    // BATCH * DI * DSTATE

typedef __attribute__((ext_vector_type(8))) __bf16 bf16x8;
typedef __attribute__((ext_vector_type(4))) float f32x4;
typedef __attribute__((ext_vector_type(8))) unsigned short u16x8;

__device__ inline float b2f(unsigned short u) {
    union { unsigned int i; float f; } v; v.i = ((unsigned int)u) << 16; return v.f;
}
__device__ inline unsigned short f2b(float f) {
    union { float f; unsigned int i; } v; v.f = f;
    unsigned int r = v.i + 0x7FFF + ((v.i >> 16) & 1);
    return (unsigned short)(r >> 16);
}
__device__ inline float softplus_f(float x) {
    return (x > 15.f) ? x : log1pf(__expf(x));
}

__device__ inline void gload16(const void* g, void* l) {
    __builtin_amdgcn_global_load_lds(
        (const __attribute__((address_space(1))) unsigned int*)g,
        (__attribute__((address_space(3))) unsigned int*)l, 16, 0, 0);
}

// ---------- converts ----------
__global__ __launch_bounds__(256) void cvt_bf16_k(const float* __restrict__ src,
                                                  unsigned short* __restrict__ dst,
                                                  int n4) {
    int i = blockIdx.x * 256 + threadIdx.x;
    if (i >= n4) return;
    float4 v = ((const float4*)src)[i];
    ushort4 o;
    o.x = f2b(v.x); o.y = f2b(v.y); o.z = f2b(v.z); o.w = f2b(v.w);
    ((ushort4*)dst)[i] = o;
}

__global__ __launch_bounds__(256) void pad_xproj_k(const float* __restrict__ src,
                                                   unsigned short* __restrict__ dst) {
    int i = blockIdx.x * 256 + threadIdx.x;   // over 128*2048
    int r = i >> 11, c = i & 2047;
    dst[i] = (r < 96) ? f2b(src[r * 2048 + c]) : (unsigned short)0;
}

__global__ __launch_bounds__(256) void cvt_dt_k(const float* __restrict__ xdbl,
                                                unsigned short* __restrict__ dt) {
    int i = blockIdx.x * 256 + threadIdx.x;   // over 8192*64
    int r = i >> 6, c = i & 63;
    dt[i] = f2b(xdbl[r * 128 + c]);
}

// ---------- GEMM: C[M,N] = A[M,K] @ Bw[N,K]^T  (bf16 in, f32 acc) ----------
// EPI: 0 = store bf16, 1 = store f32
template<int EPI>
__global__ __launch_bounds__(256) void gemm_nt(const unsigned short* __restrict__ A,
                                               const unsigned short* __restrict__ Bw,
                                               void* __restrict__ Cp,
                                               int M, int N, int K) {
    __shared__ unsigned short As[128][32];
    __shared__ unsigned short Bs[128][32];
    __shared__ float Cs[32][132];              // epilogue staging
    const int t = threadIdx.x;
    const int l = t & 63;
    const int w = t >> 6;
    const int wr = w >> 1, wc = w & 1;
    const int row0 = blockIdx.x * 128, col0 = blockIdx.y * 128;
    const int sr = t >> 2;
    const int sc = (t & 3) * 8;
    const int lr = l & 15, lk = (l >> 4) * 8;

    f32x4 acc[4][4];
#pragma unroll
    for (int m = 0; m < 4; m++)
#pragma unroll
        for (int n = 0; n < 4; n++) acc[m][n] = (f32x4){0.f, 0.f, 0.f, 0.f};

    for (int kt = 0; kt < K; kt += 32) {
        gload16(A + (size_t)(row0 + sr) * K + kt + sc, &As[sr][sc]);
        gload16(A + (size_t)(row0 + sr + 64) * K + kt + sc, &As[sr + 64][sc]);
        gload16(Bw + (size_t)(col0 + sr) * K + kt + sc, &Bs[sr][sc]);
        gload16(Bw + (size_t)(col0 + sr + 64) * K + kt + sc, &Bs[sr + 64][sc]);
        __syncthreads();
        bf16x8 af[4], bfr[4];
#pragma unroll
        for (int m = 0; m < 4; m++)
            af[m] = *(const bf16x8*)&As[wr * 64 + m * 16 + lr][lk];
#pragma unroll
        for (int n = 0; n < 4; n++)
            bfr[n] = *(const bf16x8*)&Bs[wc * 64 + n * 16 + lr][lk];
#pragma unroll
        for (int m = 0; m < 4; m++)
#pragma unroll
            for (int n = 0; n < 4; n++)
                acc[m][n] = __builtin_amdgcn_mfma_f32_16x16x32_bf16(af[m], bfr[n], acc[m][n], 0, 0, 0);
        __syncthreads();
    }

    // epilogue: C/D layout col=lane&15, row=(lane>>4)*4+i  [m89-verified]
    const int er = (l >> 4) * 4;
    const int ec = l & 15;
#pragma unroll
    for (int m = 0; m < 4; m++) {
#pragma unroll
        for (int n = 0; n < 4; n++) {
#pragma unroll
            for (int i = 0; i < 4; i++)
                Cs[wr * 16 + er + i][wc * 64 + n * 16 + ec] = acc[m][n][i];
        }
        __syncthreads();
#pragma unroll
        for (int j = 0; j < 4; j++) {
            const int f = j * 1024 + t * 4;
            const int r2 = f >> 7, col = f & 127;
            float4 v = *(const float4*)&Cs[r2][col];
            const int grow = row0 + (r2 >> 4) * 64 + m * 16 + (r2 & 15);
            const int gcol = col0 + col;
            if (EPI == 0) {
                ushort4 o;
                o.x = f2b(v.x); o.y = f2b(v.y); o.z = f2b(v.z); o.w = f2b(v.w);
                *(ushort4*)&((unsigned short*)Cp)[(size_t)grow * N + gcol] = o;
            } else {
                *(float4*)&((float*)Cp)[(size_t)grow * N + gcol] = v;
            }
        }
        __syncthreads();
    }
}

// ---------- causal depthwise conv (k=4) + SiLU, bf16 in/out ----------
__global__ __launch_bounds__(256) void conv_silu_k(const unsigned short* __restrict__ xz, // [8192][4096]
                                                   const float* __restrict__ cw,          // [2048][4]
                                                   const float* __restrict__ cb,
                                                   unsigned short* __restrict__ xact) {   // [8192][2048]
    const int t = threadIdx.x;
    const int row = blockIdx.x;        // b*2048 + l
    const int l = row & 2047;
    const int d8 = t * 8;

    float acc[8];
    float wgt[8][4];
#pragma unroll
    for (int i = 0; i < 8; i++) {
        float4 wv = *(const float4*)&cw[(d8 + i) * 4];
        wgt[i][0] = wv.x; wgt[i][1] = wv.y; wgt[i][2] = wv.z; wgt[i][3] = wv.w;
        acc[i] = cb[d8 + i];
    }
#pragma unroll
    for (int j = 0; j < 4; j++) {
        const int ls = l - 3 + j;
        if (ls < 0) continue;
        u16x8 v = *(const u16x8*)(xz + (size_t)(row - 3 + j) * 4096 + d8);
#pragma unroll
        for (int i = 0; i < 8; i++) acc[i] = fmaf(wgt[i][j], b2f(v[i]), acc[i]);
    }
    u16x8 o;
#pragma unroll
    for (int i = 0; i < 8; i++) {
        float xx = acc[i];
        o[i] = f2b(xx / (1.f + __expf(-xx)));
    }
    *(u16x8*)(xact + (size_t)row * 2048 + d8) = o;
}

// ---------- scan pass 1: local scans of segments 0..2, fused delta MFMA ----------
__global__ __launch_bounds__(256) void scan_seg1(const unsigned short* __restrict__ dtb, // [8192][64] bf16
                                                 const unsigned short* __restrict__ wdt, // [2048][64] bf16
                                                 const float* __restrict__ dt_bias,      // [2048]
                                                 const unsigned short* __restrict__ xact,
                                                 const float* __restrict__ xdbl,
                                                 const float* __restrict__ A_log,
                                                 float* __restrict__ hfin,
                                                 float* __restrict__ Pst) {
    __shared__ unsigned short dt_s[CL][64];      // 4 KB (single buf, XOR-swizzled)
    __shared__ float          dl_s[2][CL][16];   // 4 KB
    __shared__ unsigned short u_s [2][CL][16];   // 2 KB
    __shared__ float          B_s [2][CL][16];   // 4 KB

    const int t = threadIdx.x;
    const int l = t & 63;
    const int w = t >> 6;
    const int g = t >> 4, n = t & 15;
    const int lr = l & 15, lk = (l >> 4) * 8;
    const int s = blockIdx.x >> 9;              // 0..2
    const int rest = blockIdx.x & 511;
    const int b = rest >> 7;
    const int d0 = (rest & 127) << 4;
    const size_t base = (size_t)b * 2048 + (size_t)s * SEGL;

    const float Aln2 = -__expf(A_log[(d0 + g) * 16 + n]) * 1.44269504089f;
    float h = 0.f, p = 1.f;

    // Wdt fragments + bias in registers (per-lane: ch = lr)
    bf16x8 wf[2];
    wf[0] = *(const bf16x8*)(wdt + (size_t)(d0 + lr) * 64 + lk);
    wf[1] = *(const bf16x8*)(wdt + (size_t)(d0 + lr) * 64 + lk + 32);
    const float wbias = dt_bias[d0 + lr];

    auto stage_dt = [&](int c) {                 // chunk c -> dt_s (swizzled src)
        const int row = t >> 3;
        const int coff = (t & 7) << 4;           // dest byte off in row (linear)
        const int soff = coff ^ ((row & 7) << 4);
        gload16(dtb + (size_t)(base + c * CL + row) * 64 + (soff >> 1),
                &dt_s[row][coff >> 1]);
    };
    auto stage = [&](int buf, int c) {
        const int r0 = c * CL;
        if (t < 64) {       // u: 32 rows x 32 B
            gload16(xact + (size_t)(base + r0 + (t >> 1)) * 2048 + d0 + (t & 1) * 8,
                    &u_s[buf][t >> 1][(t & 1) * 8]);
        } else if (t >= 128) {  // B: 32 rows x 64 B; xdbl floats [64,80)
            const int i = t - 128;
            gload16(xdbl + (size_t)(base + r0 + (i >> 2)) * 128 + 64 + (i & 3) * 4,
                    &B_s[buf][i >> 2][(i & 3) * 4]);
        }
    };
    auto mfma_dl = [&](int buf) {                // delta = softplus(dt @ WdtT + b)
        if (w < 2) {
            const int tr = w * 16;
            const int row = tr + lr;
            f32x4 acc = (f32x4){0.f, 0.f, 0.f, 0.f};
            const char* bp = (const char*)&dt_s[0][0];
#pragma unroll
            for (int kk = 0; kk < 2; ++kk) {
                const int off = (l >> 4) * 16 + kk * 64;
                bf16x8 a = *(const bf16x8*)(bp + row * 128 + (off ^ ((row & 7) << 4)));
                acc = __builtin_amdgcn_mfma_f32_16x16x32_bf16(a, wf[kk], acc, 0, 0, 0);
            }
#pragma unroll
            for (int i = 0; i < 4; ++i)
                dl_s[buf][tr + (l >> 4) * 4 + i][lr] = softplus_f(acc[i] + wbias);
        }
    };

    stage_dt(0); stage(0, 0);
    __syncthreads();
    mfma_dl(0);
    __syncthreads();

    for (int c = 0; c < NCH2; ++c) {
        const int cur = c & 1;
        if (c + 1 < NCH2) { stage_dt(c + 1); stage(cur ^ 1, c + 1); }
        {
            const float* dlp = &dl_s[cur][0][0];
            const unsigned short* up = &u_s[cur][0][0];
            const float* bpp = &B_s[cur][0][0];
#pragma unroll 8
            for (int r = 0; r < CL; ++r) {
                const float dl = dlp[r * 16 + g];
                const float uu = b2f(up[r * 16 + g]);
                const float Bn = bpp[r * 16 + n];
                const float dA = __builtin_amdgcn_exp2f(dl * Aln2);
                h = fmaf(h, dA, dl * uu * Bn);
                p *= dA;
            }
        }
        __syncthreads();                     // retire reads + drain stage
        if (c + 1 < NCH2) mfma_dl(cur ^ 1);
        __syncthreads();                     // dl_s[cur^1] visible
    }
    const int idx = s * CHTOT + b * 32768 + (d0 + g) * 16 + n;
    hfin[idx] = h;
    Pst[idx] = p;
}

// ---------- scan fixup: sequential over 4 segments (tiny) ----------
__global__ __launch_bounds__(256) void scan_fix(const float* __restrict__ hfin,
                                                const float* __restrict__ Pst,
                                                float* __restrict__ hin) {
    const int i = blockIdx.x * 256 + threadIdx.x;   // 0..CHTOT-1
    hin[i] = 0.f;
    float h = hfin[i];
    hin[CHTOT + i] = h;
    h = fmaf(h, Pst[CHTOT + i], hfin[CHTOT + i]);
    hin[2 * CHTOT + i] = h;
    h = fmaf(h, Pst[2 * CHTOT + i], hfin[2 * CHTOT + i]);
    hin[3 * CHTOT + i] = h;
}

// ---------- scan pass 2: full scan per segment, fused delta MFMA ----------
__global__ __launch_bounds__(256) void scan_k2(const unsigned short* __restrict__ dtb,
                                               const unsigned short* __restrict__ wdt,
                                               const float* __restrict__ dt_bias,
                                               const unsigned short* __restrict__ xact,
                                               const float* __restrict__ xdbl,
                                               const unsigned short* __restrict__ xz,
                                               const float* __restrict__ A_log,
                                               const float* __restrict__ Dv,
                                               const float* __restrict__ hin,
                                               unsigned short* __restrict__ y) {
    __shared__ unsigned short dt_s[CL][64];       // 4 KB (single buf, swizzled)
    __shared__ float          dl_s[2][CL][16];    // 4 KB
    __shared__ unsigned short u_s [2][CL][16];    // 2 KB
    __shared__ float          BC_s[2][CL][32];    // 8 KB  (B | C)
    __shared__ float          hc_s[CL][16][17];   // 34 KB

    const int t = threadIdx.x;
    const int l = t & 63;
    const int w = t >> 6;
    const int g = t >> 4, n = t & 15;
    const int lr = l & 15, lk = (l >> 4) * 8;
    const int s = blockIdx.x >> 9;
    const int rest = blockIdx.x & 511;
    const int b = rest >> 7;
    const int d0 = (rest & 127) << 4;
    const size_t base = (size_t)b * 2048 + (size_t)s * SEGL;

    const float Aln2 = -__expf(A_log[(d0 + g) * 16 + n]) * 1.44269504089f;
    float h = hin[s * CHTOT + b * 32768 + (d0 + g) * 16 + n];

    const int ch = t & 15;
    const float Dch = Dv[d0 + ch];

    bf16x8 wf[2];
    wf[0] = *(const bf16x8*)(wdt + (size_t)(d0 + lr) * 64 + lk);
    wf[1] = *(const bf16x8*)(wdt + (size_t)(d0 + lr) * 64 + lk + 32);
    const float wbias = dt_bias[d0 + lr];

    auto stage_dt = [&](int c) {
        const int row = t >> 3;
        const int coff = (t & 7) << 4;
        const int soff = coff ^ ((row & 7) << 4);
        gload16(dtb + (size_t)(base + c * CL + row) * 64 + (soff >> 1),
                &dt_s[row][coff >> 1]);
    };
    auto stage = [&](int buf, int c) {
        const int r0 = c * CL;
        if (t < 64) {
            gload16(xact + (size_t)(base + r0 + (t >> 1)) * 2048 + d0 + (t & 1) * 8,
                    &u_s[buf][t >> 1][(t & 1) * 8]);
        }
        gload16(xdbl + (size_t)(base + r0 + (t >> 3)) * 128 + 64 + (t & 7) * 4,
                &BC_s[buf][t >> 3][(t & 7) * 4]);
    };
    auto mfma_dl = [&](int buf) {
        if (w < 2) {
            const int tr = w * 16;
            const int row = tr + lr;
            f32x4 acc = (f32x4){0.f, 0.f, 0.f, 0.f};
            const char* bp = (const char*)&dt_s[0][0];
#pragma unroll
            for (int kk = 0; kk < 2; ++kk) {
                const int off = (l >> 4) * 16 + kk * 64;
                bf16x8 a = *(const bf16x8*)(bp + row * 128 + (off ^ ((row & 7) << 4)));
                acc = __builtin_amdgcn_mfma_f32_16x16x32_bf16(a, wf[kk], acc, 0, 0, 0);
            }
#pragma unroll
            for (int i = 0; i < 4; ++i)
                dl_s[buf][tr + (l >> 4) * 4 + i][lr] = softplus_f(acc[i] + wbias);
        }
    };

    stage_dt(0); stage(0, 0);
    __syncthreads();
    mfma_dl(0);
    __syncthreads();

    for (int c = 0; c < NCH2; ++c) {
        const int cur = c & 1;
        if (c + 1 < NCH2) { stage_dt(c + 1); stage(cur ^ 1, c + 1); }

        // ---- phase A: recurrence ----
        {
            const float* dlp = &dl_s[cur][0][0];
            const unsigned short* up = &u_s[cur][0][0];
            const float* bcp = &BC_s[cur][0][0];
#pragma unroll 8
            for (int r = 0; r < CL; ++r) {
                const float dl = dlp[r * 16 + g];
                const float uu = b2f(up[r * 16 + g]);
                const float Bn = bcp[r * 32 + n];
                const float Cn = bcp[r * 32 + 16 + n];
                const float dA = __builtin_amdgcn_exp2f(dl * Aln2);
                h = fmaf(h, dA, dl * uu * Bn);
                hc_s[r][g][n] = h * Cn;
            }
        }
        __syncthreads();                     // hc ready; stage drained
        if (c + 1 < NCH2) mfma_dl(cur ^ 1);  // delta for next chunk

        // ---- phase B: reduce over states + gate + store ----
#pragma unroll
        for (int it = 0; it < 2; ++it) {
            const int rr = (t >> 4) + 16 * it;
            float sum = 0.f;
#pragma unroll
            for (int nn = 0; nn < 16; ++nn) sum += hc_s[rr][ch][nn];
            const float uu = b2f(u_s[cur][rr][ch]);
            const size_t row = base + (size_t)c * CL + rr;
            const float zz = b2f(xz[row * 4096 + 2048 + d0 + ch]);
            const float yy = (sum + Dch * uu) * (zz / (1.f + __expf(-zz)));
            y[row * 2048 + d0 + ch] = f2b(yy);
        }
        __syncthreads();
    }
}

extern "C" void kernel_launch(void* const* d_in, const int* in_sizes, int n_in,
                              void* d_out, int out_size, void* d_ws, size_t ws_size,
                              hipStream_t stream) {
    const float* x         = (const float*)d_in[0];
    const float* in_proj_w = (const float*)d_in[1];
    const float* conv_w    = (const float*)d_in[2];
    const float* conv_b    = (const float*)d_in[3];
    const float* x_proj_w  = (const float*)d_in[4];
    const float* dt_proj_w = (const float*)d_in[5];
    const float* dt_proj_b = (const float*)d_in[6];
    const float* A_log     = (const float*)d_in[7];
    const float* Dv        = (const float*)d_in[8];
    const float* out_proj_w= (const float*)d_in[9];
    float* out = (float*)d_out;

    char* p = (char*)d_ws;
    auto alloc = [&](size_t n) { char* r = p; p += (n + 255) & ~255ULL; return r; };
    unsigned short* xb   = (unsigned short*)alloc((size_t)NROWS * DM * 2);       // x bf16
    unsigned short* win  = (unsigned short*)alloc((size_t)4096 * DM * 2);        // in_proj bf16
    unsigned short* wxp  = (unsigned short*)alloc((size_t)128 * DI * 2);         // x_proj padded bf16
    unsigned short* wdt  = (unsigned short*)alloc((size_t)DI * DTRANK * 2);      // dt_proj bf16
    unsigned short* wout = (unsigned short*)alloc((size_t)DM * DI * 2);          // out_proj bf16
    unsigned short* xzb  = (unsigned short*)alloc((size_t)NROWS * 4096 * 2);     // xz bf16
    unsigned short* xab  = (unsigned short*)alloc((size_t)NROWS * DI * 2);       // xact bf16
    float*          xdbl = (float*)alloc((size_t)NROWS * 128 * 4);               // x_dbl f32
    unsigned short* dtb  = (unsigned short*)alloc((size_t)NROWS * DTRANK * 2);   // dt bf16
    unsigned short* yb   = (unsigned short*)alloc((size_t)NROWS * DI * 2);       // y bf16
    float*          hfin = (float*)alloc((size_t)3 * CHTOT * 4);                 // seg-local final h
    float*          Pst  = (float*)alloc((size_t)3 * CHTOT * 4);                 // seg prod(dA)
    float*          hin  = (float*)alloc((size_t)4 * CHTOT * 4);                 // exact seg h_in

    // converts
    cvt_bf16_k<<<(NROWS * DM / 4 + 255) / 256, 256, 0, stream>>>(x, xb, NROWS * DM / 4);
    cvt_bf16_k<<<(4096 * DM / 4 + 255) / 256, 256, 0, stream>>>(in_proj_w, win, 4096 * DM / 4);
    cvt_bf16_k<<<(DI * DTRANK / 4 + 255) / 256, 256, 0, stream>>>(dt_proj_w, wdt, DI * DTRANK / 4);
    cvt_bf16_k<<<(DM * DI / 4 + 255) / 256, 256, 0, stream>>>(out_proj_w, wout, DM * DI / 4);
    pad_xproj_k<<<(128 * DI) / 256, 256, 0, stream>>>(x_proj_w, wxp);

    // 1) xz = x @ in_proj^T   [8192,4096]
    gemm_nt<0><<<dim3(NROWS / 128, 4096 / 128), 256, 0, stream>>>(xb, win, xzb, NROWS, 4096, DM);
    // 2) conv + silu -> xact
    conv_silu_k<<<NROWS, 256, 0, stream>>>(xzb, conv_w, conv_b, xab);
    // 3) x_dbl = xact @ x_proj^T (padded N=128)
    gemm_nt<1><<<dim3(NROWS / 128, 1), 256, 0, stream>>>(xab, wxp, xdbl, NROWS, 128, DI);
    // 4) dt slice -> bf16
    cvt_dt_k<<<(NROWS * DTRANK) / 256, 256, 0, stream>>>(xdbl, dtb);
    // 5+6) selective scan with FUSED delta (softplus(dt@WdtT+b) via per-chunk MFMA)
    scan_seg1<<<3 * 512, 256, 0, stream>>>(dtb, wdt, dt_proj_b, xab, xdbl, A_log, hfin, Pst);
    scan_fix<<<CHTOT / 256, 256, 0, stream>>>(hfin, Pst, hin);
    scan_k2<<<4 * 512, 256, 0, stream>>>(dtb, wdt, dt_proj_b, xab, xdbl, xzb, A_log, Dv, hin, yb);
    // 7) out = y @ out_proj^T  [8192,1024] f32
    gemm_nt<1><<<dim3(NROWS / 128, DM / 128), 256, 0, stream>>>(yb, wout, out, NROWS, DM, DI);
}

// Round 15
// 510.912 us; speedup vs baseline: 1.1546x; 1.1546x over previous
//
#include <hip/hip_runtime.h>
#include <hip/hip_bf16.h>
#include <stdint.h>

#define NROWS 8192      // B*L = 4*2048
#define BATCH 4
#define DM    1024
#define DI    2048
#define DSTATE 16
#define DTRANK 64
#define CL    32        // scan chunk length
#define SEGL  512       // scan segment length (S=4 segments)
#define NCH2  16        // SEGL / CL
#define CHTOT 131072    // BATCH * DI * DSTATE

typedef __attribute__((ext_vector_type(8))) __bf16 bf16x8;
typedef __attribute__((ext_vector_type(4))) float f32x4;
typedef __attribute__((ext_vector_type(8))) unsigned short u16x8;

__device__ inline float b2f(unsigned short u) {
    union { unsigned int i; float f; } v; v.i = ((unsigned int)u) << 16; return v.f;
}
__device__ inline unsigned short f2b(float f) {
    union { float f; unsigned int i; } v; v.f = f;
    unsigned int r = v.i + 0x7FFF + ((v.i >> 16) & 1);
    return (unsigned short)(r >> 16);
}
// fast, stable softplus: max(x,0) + log(1+exp(-|x|)) — v_exp_f32 + v_log_f32 only,
// no libm log1pf (precise-path log1pf suspected ~258 cy/elem from rounds 11-12 VALUBusy).
__device__ inline float softplus_f(float x) {
    return fmaxf(x, 0.f) + __logf(1.f + __expf(-fabsf(x)));
}

__device__ inline void gload16(const void* g, void* l) {
    __builtin_amdgcn_global_load_lds(
        (const __attribute__((address_space(1))) unsigned int*)g,
        (__attribute__((address_space(3))) unsigned int*)l, 16, 0, 0);
}

// ---------- converts ----------
__global__ __launch_bounds__(256) void cvt_bf16_k(const float* __restrict__ src,
                                                  unsigned short* __restrict__ dst,
                                                  int n4) {
    int i = blockIdx.x * 256 + threadIdx.x;
    if (i >= n4) return;
    float4 v = ((const float4*)src)[i];
    ushort4 o;
    o.x = f2b(v.x); o.y = f2b(v.y); o.z = f2b(v.z); o.w = f2b(v.w);
    ((ushort4*)dst)[i] = o;
}

__global__ __launch_bounds__(256) void pad_xproj_k(const float* __restrict__ src,
                                                   unsigned short* __restrict__ dst) {
    int i = blockIdx.x * 256 + threadIdx.x;   // over 128*2048
    int r = i >> 11, c = i & 2047;
    dst[i] = (r < 96) ? f2b(src[r * 2048 + c]) : (unsigned short)0;
}

__global__ __launch_bounds__(256) void cvt_dt_k(const float* __restrict__ xdbl,
                                                unsigned short* __restrict__ dt) {
    int i = blockIdx.x * 256 + threadIdx.x;   // over 8192*64
    int r = i >> 6, c = i & 63;
    dt[i] = f2b(xdbl[r * 128 + c]);
}

// ---------- GEMM: C[M,N] = A[M,K] @ Bw[N,K]^T  (bf16 in, f32 acc) ----------
// EPI: 0 = store bf16, 1 = store f32, 2 = softplus(acc + bias[col]) -> f32
// Epilogue LDS-staged for coalesced global stores.
template<int EPI>
__global__ __launch_bounds__(256) void gemm_nt(const unsigned short* __restrict__ A,
                                               const unsigned short* __restrict__ Bw,
                                               void* __restrict__ Cp,
                                               const float* __restrict__ bias,
                                               int M, int N, int K) {
    __shared__ unsigned short As[128][32];
    __shared__ unsigned short Bs[128][32];
    __shared__ float Cs[32][132];              // epilogue staging (132: 2-way banks)
    const int t = threadIdx.x;
    const int l = t & 63;
    const int w = t >> 6;
    const int wr = w >> 1, wc = w & 1;
    const int row0 = blockIdx.x * 128, col0 = blockIdx.y * 128;
    const int sr = t >> 2;
    const int sc = (t & 3) * 8;
    const int lr = l & 15, lk = (l >> 4) * 8;

    f32x4 acc[4][4];
#pragma unroll
    for (int m = 0; m < 4; m++)
#pragma unroll
        for (int n = 0; n < 4; n++) acc[m][n] = (f32x4){0.f, 0.f, 0.f, 0.f};

    for (int kt = 0; kt < K; kt += 32) {
        gload16(A + (size_t)(row0 + sr) * K + kt + sc, &As[sr][sc]);
        gload16(A + (size_t)(row0 + sr + 64) * K + kt + sc, &As[sr + 64][sc]);
        gload16(Bw + (size_t)(col0 + sr) * K + kt + sc, &Bs[sr][sc]);
        gload16(Bw + (size_t)(col0 + sr + 64) * K + kt + sc, &Bs[sr + 64][sc]);
        __syncthreads();
        bf16x8 af[4], bfr[4];
#pragma unroll
        for (int m = 0; m < 4; m++)
            af[m] = *(const bf16x8*)&As[wr * 64 + m * 16 + lr][lk];
#pragma unroll
        for (int n = 0; n < 4; n++)
            bfr[n] = *(const bf16x8*)&Bs[wc * 64 + n * 16 + lr][lk];
#pragma unroll
        for (int m = 0; m < 4; m++)
#pragma unroll
            for (int n = 0; n < 4; n++)
                acc[m][n] = __builtin_amdgcn_mfma_f32_16x16x32_bf16(af[m], bfr[n], acc[m][n], 0, 0, 0);
        __syncthreads();
    }

    // epilogue: C/D layout col=lane&15, row=(lane>>4)*4+i  [m89-verified]
    const int er = (l >> 4) * 4;
    const int ec = l & 15;
#pragma unroll
    for (int m = 0; m < 4; m++) {
#pragma unroll
        for (int n = 0; n < 4; n++) {
#pragma unroll
            for (int i = 0; i < 4; i++)
                Cs[wr * 16 + er + i][wc * 64 + n * 16 + ec] = acc[m][n][i];
        }
        __syncthreads();
#pragma unroll
        for (int j = 0; j < 4; j++) {
            const int f = j * 1024 + t * 4;
            const int r2 = f >> 7, col = f & 127;
            float4 v = *(const float4*)&Cs[r2][col];
            const int grow = row0 + (r2 >> 4) * 64 + m * 16 + (r2 & 15);
            const int gcol = col0 + col;
            if (EPI == 0) {
                ushort4 o;
                o.x = f2b(v.x); o.y = f2b(v.y); o.z = f2b(v.z); o.w = f2b(v.w);
                *(ushort4*)&((unsigned short*)Cp)[(size_t)grow * N + gcol] = o;
            } else if (EPI == 1) {
                *(float4*)&((float*)Cp)[(size_t)grow * N + gcol] = v;
            } else {
                float4 o;
                o.x = softplus_f(v.x + bias[gcol]);
                o.y = softplus_f(v.y + bias[gcol + 1]);
                o.z = softplus_f(v.z + bias[gcol + 2]);
                o.w = softplus_f(v.w + bias[gcol + 3]);
                *(float4*)&((float*)Cp)[(size_t)grow * N + gcol] = o;
            }
        }
        __syncthreads();
    }
}

// ---------- causal depthwise conv (k=4) + SiLU, bf16 in/out ----------
__global__ __launch_bounds__(256) void conv_silu_k(const unsigned short* __restrict__ xz, // [8192][4096]
                                                   const float* __restrict__ cw,          // [2048][4]
                                                   const float* __restrict__ cb,
                                                   unsigned short* __restrict__ xact) {   // [8192][2048]
    const int t = threadIdx.x;
    const int row = blockIdx.x;        // b*2048 + l
    const int l = row & 2047;
    const int d8 = t * 8;

    float acc[8];
    float wgt[8][4];
#pragma unroll
    for (int i = 0; i < 8; i++) {
        float4 wv = *(const float4*)&cw[(d8 + i) * 4];
        wgt[i][0] = wv.x; wgt[i][1] = wv.y; wgt[i][2] = wv.z; wgt[i][3] = wv.w;
        acc[i] = cb[d8 + i];
    }
#pragma unroll
    for (int j = 0; j < 4; j++) {
        const int ls = l - 3 + j;
        if (ls < 0) continue;
        u16x8 v = *(const u16x8*)(xz + (size_t)(row - 3 + j) * 4096 + d8);
#pragma unroll
        for (int i = 0; i < 8; i++) acc[i] = fmaf(wgt[i][j], b2f(v[i]), acc[i]);
    }
    u16x8 o;
#pragma unroll
    for (int i = 0; i < 8; i++) {
        float xx = acc[i];
        o[i] = f2b(xx / (1.f + __expf(-xx)));
    }
    *(u16x8*)(xact + (size_t)row * 2048 + d8) = o;
}

// ---------- scan pass 1: local scans of segments 0..2, recurrence only ----------
__global__ __launch_bounds__(256) void scan_seg1(const float* __restrict__ dlt,
                                                 const unsigned short* __restrict__ xact,
                                                 const float* __restrict__ xdbl,
                                                 const float* __restrict__ A_log,
                                                 float* __restrict__ hfin,
                                                 float* __restrict__ Pst) {
    __shared__ float          dl_s[2][CL][16];   // 4 KB
    __shared__ unsigned short u_s [2][CL][16];   // 2 KB
    __shared__ float          B_s [2][CL][16];   // 4 KB

    const int t = threadIdx.x;
    const int g = t >> 4, n = t & 15;
    const int s = blockIdx.x >> 9;              // 0..2
    const int rest = blockIdx.x & 511;
    const int b = rest >> 7;
    const int d0 = (rest & 127) << 4;
    const size_t base = (size_t)b * 2048 + (size_t)s * SEGL;

    const float Aln2 = -__expf(A_log[(d0 + g) * 16 + n]) * 1.44269504089f;
    float h = 0.f, p = 1.f;

    auto stage = [&](int buf, int c) {
        const int r0 = c * CL;
        if (t < 128) {      // dl: 32 rows x 64 B (waves 0,1)
            gload16(dlt + (size_t)(base + r0 + (t >> 2)) * 2048 + d0 + (t & 3) * 4,
                    &dl_s[buf][t >> 2][(t & 3) * 4]);
        } else {            // B: 32 rows x 64 B (waves 2,3); xdbl floats [64,80)
            const int i = t - 128;
            gload16(xdbl + (size_t)(base + r0 + (i >> 2)) * 128 + 64 + (i & 3) * 4,
                    &B_s[buf][i >> 2][(i & 3) * 4]);
        }
        if (t < 64) {       // u: 32 rows x 32 B (wave 0, second load)
            gload16(xact + (size_t)(base + r0 + (t >> 1)) * 2048 + d0 + (t & 1) * 8,
                    &u_s[buf][t >> 1][(t & 1) * 8]);
        }
    };

    stage(0, 0);
    __syncthreads();

    for (int c = 0; c < NCH2; ++c) {
        const int cur = c & 1;
        if (c + 1 < NCH2) stage(cur ^ 1, c + 1);
        const float* dlp = &dl_s[cur][0][0];
        const unsigned short* up = &u_s[cur][0][0];
        const float* bp = &B_s[cur][0][0];
#pragma unroll 8
        for (int r = 0; r < CL; ++r) {
            const float dl = dlp[r * 16 + g];
            const float uu = b2f(up[r * 16 + g]);
            const float Bn = bp[r * 16 + n];
            const float dA = __builtin_amdgcn_exp2f(dl * Aln2);
            h = fmaf(h, dA, dl * uu * Bn);
            p *= dA;
        }
        __syncthreads();
    }
    const int idx = s * CHTOT + b * 32768 + (d0 + g) * 16 + n;
    hfin[idx] = h;
    Pst[idx] = p;
}

// ---------- scan fixup: sequential over 4 segments (tiny) ----------
__global__ __launch_bounds__(256) void scan_fix(const float* __restrict__ hfin,
                                                const float* __restrict__ Pst,
                                                float* __restrict__ hin) {
    const int i = blockIdx.x * 256 + threadIdx.x;   // 0..CHTOT-1
    hin[i] = 0.f;
    float h = hfin[i];
    hin[CHTOT + i] = h;
    h = fmaf(h, Pst[CHTOT + i], hfin[CHTOT + i]);
    hin[2 * CHTOT + i] = h;
    h = fmaf(h, Pst[2 * CHTOT + i], hfin[2 * CHTOT + i]);
    hin[3 * CHTOT + i] = h;
}

// ---------- scan pass 2: full scan per segment from exact h_in ----------
__global__ __launch_bounds__(256) void scan_k2(const float* __restrict__ dlt,
                                               const unsigned short* __restrict__ xact,
                                               const float* __restrict__ xdbl,
                                               const unsigned short* __restrict__ xz,
                                               const float* __restrict__ A_log,
                                               const float* __restrict__ Dv,
                                               const float* __restrict__ hin,
                                               unsigned short* __restrict__ y) {
    __shared__ float          dl_s[2][CL][16];    // 4 KB
    __shared__ unsigned short u_s [2][CL][16];    // 2 KB
    __shared__ float          BC_s[2][CL][32];    // 8 KB  (B | C)
    __shared__ float          hc_s[CL][16][17];   // 34 KB

    const int t = threadIdx.x;
    const int g = t >> 4, n = t & 15;
    const int s = blockIdx.x >> 9;
    const int rest = blockIdx.x & 511;
    const int b = rest >> 7;
    const int d0 = (rest & 127) << 4;
    const size_t base = (size_t)b * 2048 + (size_t)s * SEGL;

    const float Aln2 = -__expf(A_log[(d0 + g) * 16 + n]) * 1.44269504089f;
    float h = hin[s * CHTOT + b * 32768 + (d0 + g) * 16 + n];

    const int ch = t & 15;
    const float Dch = Dv[d0 + ch];

    auto stage = [&](int buf, int c) {
        const int r0 = c * CL;
        if (t < 128) {
            gload16(dlt + (size_t)(base + r0 + (t >> 2)) * 2048 + d0 + (t & 3) * 4,
                    &dl_s[buf][t >> 2][(t & 3) * 4]);
        } else if (t < 192) {
            const int i = t - 128;
            gload16(xact + (size_t)(base + r0 + (i >> 1)) * 2048 + d0 + (i & 1) * 8,
                    &u_s[buf][i >> 1][(i & 1) * 8]);
        }
        gload16(xdbl + (size_t)(base + r0 + (t >> 3)) * 128 + 64 + (t & 7) * 4,
                &BC_s[buf][t >> 3][(t & 7) * 4]);
    };

    stage(0, 0);
    __syncthreads();

    for (int c = 0; c < NCH2; ++c) {
        const int cur = c & 1;
        if (c + 1 < NCH2) stage(cur ^ 1, c + 1);

        // ---- phase A: recurrence, no cross-lane ops ----
        {
            const float* dlp = &dl_s[cur][0][0];
            const unsigned short* up = &u_s[cur][0][0];
            const float* bcp = &BC_s[cur][0][0];
#pragma unroll 8
            for (int r = 0; r < CL; ++r) {
                const float dl = dlp[r * 16 + g];
                const float uu = b2f(up[r * 16 + g]);
                const float Bn = bcp[r * 32 + n];
                const float Cn = bcp[r * 32 + 16 + n];
                const float dA = __builtin_amdgcn_exp2f(dl * Aln2);
                h = fmaf(h, dA, dl * uu * Bn);
                hc_s[r][g][n] = h * Cn;
            }
        }
        __syncthreads();

        // ---- phase B: reduce over states + gate + store (2-way banks) ----
#pragma unroll
        for (int it = 0; it < 2; ++it) {
            const int rr = (t >> 4) + 16 * it;
            float sum = 0.f;
#pragma unroll
            for (int nn = 0; nn < 16; ++nn) sum += hc_s[rr][ch][nn];
            const float uu = b2f(u_s[cur][rr][ch]);
            const size_t row = base + (size_t)c * CL + rr;
            const float zz = b2f(xz[row * 4096 + 2048 + d0 + ch]);
            const float yy = (sum + Dch * uu) * (zz / (1.f + __expf(-zz)));
            y[row * 2048 + d0 + ch] = f2b(yy);
        }
        __syncthreads();
    }
}

extern "C" void kernel_launch(void* const* d_in, const int* in_sizes, int n_in,
                              void* d_out, int out_size, void* d_ws, size_t ws_size,
                              hipStream_t stream) {
    const float* x         = (const float*)d_in[0];
    const float* in_proj_w = (const float*)d_in[1];
    const float* conv_w    = (const float*)d_in[2];
    const float* conv_b    = (const float*)d_in[3];
    const float* x_proj_w  = (const float*)d_in[4];
    const float* dt_proj_w = (const float*)d_in[5];
    const float* dt_proj_b = (const float*)d_in[6];
    const float* A_log     = (const float*)d_in[7];
    const float* Dv        = (const float*)d_in[8];
    const float* out_proj_w= (const float*)d_in[9];
    float* out = (float*)d_out;

    char* p = (char*)d_ws;
    auto alloc = [&](size_t n) { char* r = p; p += (n + 255) & ~255ULL; return r; };
    unsigned short* xb   = (unsigned short*)alloc((size_t)NROWS * DM * 2);       // x bf16
    unsigned short* win  = (unsigned short*)alloc((size_t)4096 * DM * 2);        // in_proj bf16
    unsigned short* wxp  = (unsigned short*)alloc((size_t)128 * DI * 2);         // x_proj padded bf16
    unsigned short* wdt  = (unsigned short*)alloc((size_t)DI * DTRANK * 2);      // dt_proj bf16
    unsigned short* wout = (unsigned short*)alloc((size_t)DM * DI * 2);          // out_proj bf16
    unsigned short* xzb  = (unsigned short*)alloc((size_t)NROWS * 4096 * 2);     // xz bf16
    unsigned short* xab  = (unsigned short*)alloc((size_t)NROWS * DI * 2);       // xact bf16
    float*          xdbl = (float*)alloc((size_t)NROWS * 128 * 4);               // x_dbl f32
    unsigned short* dtb  = (unsigned short*)alloc((size_t)NROWS * DTRANK * 2);   // dt bf16
    float*          dlt  = (float*)alloc((size_t)NROWS * DI * 4);                // delta f32
    unsigned short* yb   = (unsigned short*)alloc((size_t)NROWS * DI * 2);       // y bf16
    float*          hfin = (float*)alloc((size_t)3 * CHTOT * 4);                 // seg-local final h
    float*          Pst  = (float*)alloc((size_t)3 * CHTOT * 4);                 // seg prod(dA)
    float*          hin  = (float*)alloc((size_t)4 * CHTOT * 4);                 // exact seg h_in

    // converts
    cvt_bf16_k<<<(NROWS * DM / 4 + 255) / 256, 256, 0, stream>>>(x, xb, NROWS * DM / 4);
    cvt_bf16_k<<<(4096 * DM / 4 + 255) / 256, 256, 0, stream>>>(in_proj_w, win, 4096 * DM / 4);
    cvt_bf16_k<<<(DI * DTRANK / 4 + 255) / 256, 256, 0, stream>>>(dt_proj_w, wdt, DI * DTRANK / 4);
    cvt_bf16_k<<<(DM * DI / 4 + 255) / 256, 256, 0, stream>>>(out_proj_w, wout, DM * DI / 4);
    pad_xproj_k<<<(128 * DI) / 256, 256, 0, stream>>>(x_proj_w, wxp);

    // 1) xz = x @ in_proj^T   [8192,4096]
    gemm_nt<0><<<dim3(NROWS / 128, 4096 / 128), 256, 0, stream>>>(xb, win, xzb, nullptr, NROWS, 4096, DM);
    // 2) conv + silu -> xact
    conv_silu_k<<<NROWS, 256, 0, stream>>>(xzb, conv_w, conv_b, xab);
    // 3) x_dbl = xact @ x_proj^T (padded N=128)
    gemm_nt<1><<<dim3(NROWS / 128, 1), 256, 0, stream>>>(xab, wxp, xdbl, nullptr, NROWS, 128, DI);
    // 4) dt slice -> bf16
    cvt_dt_k<<<(NROWS * DTRANK) / 256, 256, 0, stream>>>(xdbl, dtb);
    // 5) delta = softplus(dt @ dt_proj^T + b)  [8192,2048] f32  (fast softplus)
    gemm_nt<2><<<dim3(NROWS / 128, DI / 128), 256, 0, stream>>>(dtb, wdt, dlt, dt_proj_b, NROWS, DI, DTRANK);
    // 6) selective scan, two-pass chunked (S=4): local scans -> fixup -> full scan
    scan_seg1<<<3 * 512, 256, 0, stream>>>(dlt, xab, xdbl, A_log, hfin, Pst);
    scan_fix<<<CHTOT / 256, 256, 0, stream>>>(hfin, Pst, hin);
    scan_k2<<<4 * 512, 256, 0, stream>>>(dlt, xab, xdbl, xzb, A_log, Dv, hin, yb);
    // 7) out = y @ out_proj^T  [8192,1024] f32
    gemm_nt<1><<<dim3(NROWS / 128, DM / 128), 256, 0, stream>>>(yb, wout, out, nullptr, NROWS, DM, DI);
}

// Round 17
// 495.982 us; speedup vs baseline: 1.1894x; 1.0301x over previous
//
#include <hip/hip_runtime.h>
#include <hip/hip_bf16.h>
#include <stdint.h>

#define NROWS 8192      // B*L = 4*2048
#define BATCH 4
#define DM    1024
#define DI    2048
#define DSTATE 16
#define DTRANK 64
#define CL    32        // seg1 chunk length
#define CL2   16        // scan_k2 chunk length (small -> 24.5 KB LDS -> 6 blocks/CU)
#define SEGL  512       // scan segment length (S=4 segments)
#define NCH2  16        // SEGL / CL
#define NCHK  32        // SEGL / CL2
#define CHTOT 131072    // BATCH * DI * DSTATE

typedef __attribute__((ext_vector_type(8))) __bf16 bf16x8;
typedef __attribute__((ext_vector_type(4))) float f32x4;
typedef __attribute__((ext_vector_type(8))) unsigned short u16x8;

__device__ inline float b2f(unsigned short u) {
    union { unsigned int i; float f; } v; v.i = ((unsigned int)u) << 16; return v.f;
}
__device__ inline unsigned short f2b(float f) {
    union { float f; unsigned int i; } v; v.f = f;
    unsigned int r = v.i + 0x7FFF + ((v.i >> 16) & 1);
    return (unsigned short)(r >> 16);
}
// fast, stable softplus: max(x,0) + log(1+exp(-|x|)) — v_exp_f32 + v_log_f32 only.
__device__ inline float softplus_f(float x) {
    return fmaxf(x, 0.f) + __logf(1.f + __expf(-fabsf(x)));
}

__device__ inline void gload16(const void* g, void* l) {
    __builtin_amdgcn_global_load_lds(
        (const __attribute__((address_space(1))) unsigned int*)g,
        (__attribute__((address_space(3))) unsigned int*)l, 16, 0, 0);
}

// ---------- converts ----------
__global__ __launch_bounds__(256) void cvt_bf16_k(const float* __restrict__ src,
                                                  unsigned short* __restrict__ dst,
                                                  int n4) {
    int i = blockIdx.x * 256 + threadIdx.x;
    if (i >= n4) return;
    float4 v = ((const float4*)src)[i];
    ushort4 o;
    o.x = f2b(v.x); o.y = f2b(v.y); o.z = f2b(v.z); o.w = f2b(v.w);
    ((ushort4*)dst)[i] = o;
}

__global__ __launch_bounds__(256) void pad_xproj_k(const float* __restrict__ src,
                                                   unsigned short* __restrict__ dst) {
    int i = blockIdx.x * 256 + threadIdx.x;   // over 128*2048
    int r = i >> 11, c = i & 2047;
    dst[i] = (r < 96) ? f2b(src[r * 2048 + c]) : (unsigned short)0;
}

__global__ __launch_bounds__(256) void cvt_dt_k(const float* __restrict__ xdbl,
                                                unsigned short* __restrict__ dt) {
    int i = blockIdx.x * 256 + threadIdx.x;   // over 8192*64
    int r = i >> 6, c = i & 63;
    dt[i] = f2b(xdbl[r * 128 + c]);
}

// ---------- GEMM: C[M,N] = A[M,K] @ Bw[N,K]^T  (bf16 in, f32 acc) ----------
// EPI: 0 = store bf16, 1 = store f32, 2 = softplus(acc + bias[col]) -> f32
template<int EPI>
__global__ __launch_bounds__(256) void gemm_nt(const unsigned short* __restrict__ A,
                                               const unsigned short* __restrict__ Bw,
                                               void* __restrict__ Cp,
                                               const float* __restrict__ bias,
                                               int M, int N, int K) {
    __shared__ unsigned short As[128][32];
    __shared__ unsigned short Bs[128][32];
    __shared__ float Cs[32][132];              // epilogue staging (132: 2-way banks)
    const int t = threadIdx.x;
    const int l = t & 63;
    const int w = t >> 6;
    const int wr = w >> 1, wc = w & 1;
    const int row0 = blockIdx.x * 128, col0 = blockIdx.y * 128;
    const int sr = t >> 2;
    const int sc = (t & 3) * 8;
    const int lr = l & 15, lk = (l >> 4) * 8;

    f32x4 acc[4][4];
#pragma unroll
    for (int m = 0; m < 4; m++)
#pragma unroll
        for (int n = 0; n < 4; n++) acc[m][n] = (f32x4){0.f, 0.f, 0.f, 0.f};

    for (int kt = 0; kt < K; kt += 32) {
        gload16(A + (size_t)(row0 + sr) * K + kt + sc, &As[sr][sc]);
        gload16(A + (size_t)(row0 + sr + 64) * K + kt + sc, &As[sr + 64][sc]);
        gload16(Bw + (size_t)(col0 + sr) * K + kt + sc, &Bs[sr][sc]);
        gload16(Bw + (size_t)(col0 + sr + 64) * K + kt + sc, &Bs[sr + 64][sc]);
        __syncthreads();
        bf16x8 af[4], bfr[4];
#pragma unroll
        for (int m = 0; m < 4; m++)
            af[m] = *(const bf16x8*)&As[wr * 64 + m * 16 + lr][lk];
#pragma unroll
        for (int n = 0; n < 4; n++)
            bfr[n] = *(const bf16x8*)&Bs[wc * 64 + n * 16 + lr][lk];
#pragma unroll
        for (int m = 0; m < 4; m++)
#pragma unroll
            for (int n = 0; n < 4; n++)
                acc[m][n] = __builtin_amdgcn_mfma_f32_16x16x32_bf16(af[m], bfr[n], acc[m][n], 0, 0, 0);
        __syncthreads();
    }

    // epilogue: C/D layout col=lane&15, row=(lane>>4)*4+i  [m89-verified]
    const int er = (l >> 4) * 4;
    const int ec = l & 15;
#pragma unroll
    for (int m = 0; m < 4; m++) {
#pragma unroll
        for (int n = 0; n < 4; n++) {
#pragma unroll
            for (int i = 0; i < 4; i++)
                Cs[wr * 16 + er + i][wc * 64 + n * 16 + ec] = acc[m][n][i];
        }
        __syncthreads();
#pragma unroll
        for (int j = 0; j < 4; j++) {
            const int f = j * 1024 + t * 4;
            const int r2 = f >> 7, col = f & 127;
            float4 v = *(const float4*)&Cs[r2][col];
            const int grow = row0 + (r2 >> 4) * 64 + m * 16 + (r2 & 15);
            const int gcol = col0 + col;
            if (EPI == 0) {
                ushort4 o;
                o.x = f2b(v.x); o.y = f2b(v.y); o.z = f2b(v.z); o.w = f2b(v.w);
                *(ushort4*)&((unsigned short*)Cp)[(size_t)grow * N + gcol] = o;
            } else if (EPI == 1) {
                *(float4*)&((float*)Cp)[(size_t)grow * N + gcol] = v;
            } else {
                float4 o;
                o.x = softplus_f(v.x + bias[gcol]);
                o.y = softplus_f(v.y + bias[gcol + 1]);
                o.z = softplus_f(v.z + bias[gcol + 2]);
                o.w = softplus_f(v.w + bias[gcol + 3]);
                *(float4*)&((float*)Cp)[(size_t)grow * N + gcol] = o;
            }
        }
        __syncthreads();
    }
}

// ---------- causal depthwise conv (k=4) + SiLU, bf16 in/out ----------
__global__ __launch_bounds__(256) void conv_silu_k(const unsigned short* __restrict__ xz, // [8192][4096]
                                                   const float* __restrict__ cw,          // [2048][4]
                                                   const float* __restrict__ cb,
                                                   unsigned short* __restrict__ xact) {   // [8192][2048]
    const int t = threadIdx.x;
    const int row = blockIdx.x;        // b*2048 + l
    const int l = row & 2047;
    const int d8 = t * 8;

    float acc[8];
    float wgt[8][4];
#pragma unroll
    for (int i = 0; i < 8; i++) {
        float4 wv = *(const float4*)&cw[(d8 + i) * 4];
        wgt[i][0] = wv.x; wgt[i][1] = wv.y; wgt[i][2] = wv.z; wgt[i][3] = wv.w;
        acc[i] = cb[d8 + i];
    }
#pragma unroll
    for (int j = 0; j < 4; j++) {
        const int ls = l - 3 + j;
        if (ls < 0) continue;
        u16x8 v = *(const u16x8*)(xz + (size_t)(row - 3 + j) * 4096 + d8);
#pragma unroll
        for (int i = 0; i < 8; i++) acc[i] = fmaf(wgt[i][j], b2f(v[i]), acc[i]);
    }
    u16x8 o;
#pragma unroll
    for (int i = 0; i < 8; i++) {
        float xx = acc[i];
        o[i] = f2b(xx / (1.f + __expf(-xx)));
    }
    *(u16x8*)(xact + (size_t)row * 2048 + d8) = o;
}

// ---------- scan pass 1: local scans of segments 0..2, recurrence only ----------
__global__ __launch_bounds__(256) void scan_seg1(const float* __restrict__ dlt,
                                                 const unsigned short* __restrict__ xact,
                                                 const float* __restrict__ xdbl,
                                                 const float* __restrict__ A_log,
                                                 float* __restrict__ hfin,
                                                 float* __restrict__ Pst) {
    __shared__ float          dl_s[2][CL][16];   // 4 KB
    __shared__ unsigned short u_s [2][CL][16];   // 2 KB
    __shared__ float          B_s [2][CL][16];   // 4 KB

    const int t = threadIdx.x;
    const int g = t >> 4, n = t & 15;
    const int s = blockIdx.x >> 9;              // 0..2
    const int rest = blockIdx.x & 511;
    const int b = rest >> 7;
    const int d0 = (rest & 127) << 4;
    const size_t base = (size_t)b * 2048 + (size_t)s * SEGL;

    const float Aln2 = -__expf(A_log[(d0 + g) * 16 + n]) * 1.44269504089f;
    float h = 0.f, p = 1.f;

    auto stage = [&](int buf, int c) {
        const int r0 = c * CL;
        if (t < 128) {      // dl: 32 rows x 64 B (waves 0,1)
            gload16(dlt + (size_t)(base + r0 + (t >> 2)) * 2048 + d0 + (t & 3) * 4,
                    &dl_s[buf][t >> 2][(t & 3) * 4]);
        } else {            // B: 32 rows x 64 B (waves 2,3); xdbl floats [64,80)
            const int i = t - 128;
            gload16(xdbl + (size_t)(base + r0 + (i >> 2)) * 128 + 64 + (i & 3) * 4,
                    &B_s[buf][i >> 2][(i & 3) * 4]);
        }
        if (t < 64) {       // u: 32 rows x 32 B (wave 0, second load)
            gload16(xact + (size_t)(base + r0 + (t >> 1)) * 2048 + d0 + (t & 1) * 8,
                    &u_s[buf][t >> 1][(t & 1) * 8]);
        }
    };

    stage(0, 0);
    __syncthreads();

    for (int c = 0; c < NCH2; ++c) {
        const int cur = c & 1;
        if (c + 1 < NCH2) stage(cur ^ 1, c + 1);
        const float* dlp = &dl_s[cur][0][0];
        const unsigned short* up = &u_s[cur][0][0];
        const float* bp = &B_s[cur][0][0];
#pragma unroll 8
        for (int r = 0; r < CL; ++r) {
            const float dl = dlp[r * 16 + g];
            const float uu = b2f(up[r * 16 + g]);
            const float Bn = bp[r * 16 + n];
            const float dA = __builtin_amdgcn_exp2f(dl * Aln2);
            h = fmaf(h, dA, dl * uu * Bn);
            p *= dA;
        }
        __syncthreads();
    }
    const int idx = s * CHTOT + b * 32768 + (d0 + g) * 16 + n;
    hfin[idx] = h;
    Pst[idx] = p;
}

// ---------- scan fixup: sequential over 4 segments (tiny) ----------
__global__ __launch_bounds__(256) void scan_fix(const float* __restrict__ hfin,
                                                const float* __restrict__ Pst,
                                                float* __restrict__ hin) {
    const int i = blockIdx.x * 256 + threadIdx.x;   // 0..CHTOT-1
    hin[i] = 0.f;
    float h = hfin[i];
    hin[CHTOT + i] = h;
    h = fmaf(h, Pst[CHTOT + i], hfin[CHTOT + i]);
    hin[2 * CHTOT + i] = h;
    h = fmaf(h, Pst[2 * CHTOT + i], hfin[2 * CHTOT + i]);
    hin[3 * CHTOT + i] = h;
}

// ---------- scan pass 2: full scan per segment from exact h_in ----------
// CL2=16 -> LDS 24.5 KB -> 6 blocks/CU (was 3) for latency hiding.
__global__ __launch_bounds__(256) void scan_k2(const float* __restrict__ dlt,
                                               const unsigned short* __restrict__ xact,
                                               const float* __restrict__ xdbl,
                                               const unsigned short* __restrict__ xz,
                                               const float* __restrict__ A_log,
                                               const float* __restrict__ Dv,
                                               const float* __restrict__ hin,
                                               unsigned short* __restrict__ y) {
    __shared__ float          dl_s[2][CL2][16];    // 2 KB
    __shared__ unsigned short u_s [2][CL2][16];    // 1 KB
    __shared__ float          BC_s[2][CL2][32];    // 4 KB  (B | C)
    __shared__ float          hc_s[CL2][16][17];   // 17.4 KB

    const int t = threadIdx.x;
    const int g = t >> 4, n = t & 15;
    const int s = blockIdx.x >> 9;
    const int rest = blockIdx.x & 511;
    const int b = rest >> 7;
    const int d0 = (rest & 127) << 4;
    const size_t base = (size_t)b * 2048 + (size_t)s * SEGL;

    const float Aln2 = -__expf(A_log[(d0 + g) * 16 + n]) * 1.44269504089f;
    float h = hin[s * CHTOT + b * 32768 + (d0 + g) * 16 + n];

    const int ch = n;                 // phase B: one output per thread (rr=g, ch=n)
    const float Dch = Dv[d0 + ch];

    auto stage = [&](int buf, int c) {
        const int r0 = c * CL2;
        if (t < 64) {                 // dl: 16 rows x 64 B (wave 0)
            gload16(dlt + (size_t)(base + r0 + (t >> 2)) * 2048 + d0 + (t & 3) * 4,
                    &dl_s[buf][t >> 2][(t & 3) * 4]);
        } else if (t < 96) {          // u: 16 rows x 32 B (half wave 1, lane-linear)
            const int i = t - 64;
            gload16(xact + (size_t)(base + r0 + (i >> 1)) * 2048 + d0 + (i & 1) * 8,
                    &u_s[buf][i >> 1][(i & 1) * 8]);
        } else if (t >= 128) {        // BC: 16 rows x 128 B (waves 2,3)
            const int i = t - 128;
            gload16(xdbl + (size_t)(base + r0 + (i >> 3)) * 128 + 64 + (i & 7) * 4,
                    &BC_s[buf][i >> 3][(i & 7) * 4]);
        }
    };

    stage(0, 0);
    __syncthreads();

    for (int c = 0; c < NCHK; ++c) {
        const int cur = c & 1;
        if (c + 1 < NCHK) stage(cur ^ 1, c + 1);

        // ---- phase A: recurrence, no cross-lane ops ----
        {
            const float* dlp = &dl_s[cur][0][0];
            const unsigned short* up = &u_s[cur][0][0];
            const float* bcp = &BC_s[cur][0][0];
#pragma unroll 8
            for (int r = 0; r < CL2; ++r) {
                const float dl = dlp[r * 16 + g];
                const float uu = b2f(up[r * 16 + g]);
                const float Bn = bcp[r * 32 + n];
                const float Cn = bcp[r * 32 + 16 + n];
                const float dA = __builtin_amdgcn_exp2f(dl * Aln2);
                h = fmaf(h, dA, dl * uu * Bn);
                hc_s[r][g][n] = h * Cn;
            }
        }
        __syncthreads();

        // ---- phase B: one (row, ch) per thread; exact 2-way banks ----
        {
            const int rr = g;
            float sum = 0.f;
#pragma unroll
            for (int nn = 0; nn < 16; ++nn) sum += hc_s[rr][ch][nn];
            const float uu = b2f(u_s[cur][rr][ch]);
            const size_t row = base + (size_t)c * CL2 + rr;
            const float zz = b2f(xz[row * 4096 + 2048 + d0 + ch]);
            const float yy = (sum + Dch * uu) * (zz / (1.f + __expf(-zz)));
            y[row * 2048 + d0 + ch] = f2b(yy);
        }
        __syncthreads();
    }
}

extern "C" void kernel_launch(void* const* d_in, const int* in_sizes, int n_in,
                              void* d_out, int out_size, void* d_ws, size_t ws_size,
                              hipStream_t stream) {
    const float* x         = (const float*)d_in[0];
    const float* in_proj_w = (const float*)d_in[1];
    const float* conv_w    = (const float*)d_in[2];
    const float* conv_b    = (const float*)d_in[3];
    const float* x_proj_w  = (const float*)d_in[4];
    const float* dt_proj_w = (const float*)d_in[5];
    const float* dt_proj_b = (const float*)d_in[6];
    const float* A_log     = (const float*)d_in[7];
    const float* Dv        = (const float*)d_in[8];
    const float* out_proj_w= (const float*)d_in[9];
    float* out = (float*)d_out;

    char* p = (char*)d_ws;
    auto alloc = [&](size_t n) { char* r = p; p += (n + 255) & ~255ULL; return r; };
    unsigned short* xb   = (unsigned short*)alloc((size_t)NROWS * DM * 2);       // x bf16
    unsigned short* win  = (unsigned short*)alloc((size_t)4096 * DM * 2);        // in_proj bf16
    unsigned short* wxp  = (unsigned short*)alloc((size_t)128 * DI * 2);         // x_proj padded bf16
    unsigned short* wdt  = (unsigned short*)alloc((size_t)DI * DTRANK * 2);      // dt_proj bf16
    unsigned short* wout = (unsigned short*)alloc((size_t)DM * DI * 2);          // out_proj bf16
    unsigned short* xzb  = (unsigned short*)alloc((size_t)NROWS * 4096 * 2);     // xz bf16
    unsigned short* xab  = (unsigned short*)alloc((size_t)NROWS * DI * 2);       // xact bf16
    float*          xdbl = (float*)alloc((size_t)NROWS * 128 * 4);               // x_dbl f32
    unsigned short* dtb  = (unsigned short*)alloc((size_t)NROWS * DTRANK * 2);   // dt bf16
    float*          dlt  = (float*)alloc((size_t)NROWS * DI * 4);                // delta f32
    unsigned short* yb   = (unsigned short*)alloc((size_t)NROWS * DI * 2);       // y bf16
    float*          hfin = (float*)alloc((size_t)3 * CHTOT * 4);                 // seg-local final h
    float*          Pst  = (float*)alloc((size_t)3 * CHTOT * 4);                 // seg prod(dA)
    float*          hin  = (float*)alloc((size_t)4 * CHTOT * 4);                 // exact seg h_in

    // converts
    cvt_bf16_k<<<(NROWS * DM / 4 + 255) / 256, 256, 0, stream>>>(x, xb, NROWS * DM / 4);
    cvt_bf16_k<<<(4096 * DM / 4 + 255) / 256, 256, 0, stream>>>(in_proj_w, win, 4096 * DM / 4);
    cvt_bf16_k<<<(DI * DTRANK / 4 + 255) / 256, 256, 0, stream>>>(dt_proj_w, wdt, DI * DTRANK / 4);
    cvt_bf16_k<<<(DM * DI / 4 + 255) / 256, 256, 0, stream>>>(out_proj_w, wout, DM * DI / 4);
    pad_xproj_k<<<(128 * DI) / 256, 256, 0, stream>>>(x_proj_w, wxp);

    // 1) xz = x @ in_proj^T   [8192,4096]
    gemm_nt<0><<<dim3(NROWS / 128, 4096 / 128), 256, 0, stream>>>(xb, win, xzb, nullptr, NROWS, 4096, DM);
    // 2) conv + silu -> xact
    conv_silu_k<<<NROWS, 256, 0, stream>>>(xzb, conv_w, conv_b, xab);
    // 3) x_dbl = xact @ x_proj^T (padded N=128)
    gemm_nt<1><<<dim3(NROWS / 128, 1), 256, 0, stream>>>(xab, wxp, xdbl, nullptr, NROWS, 128, DI);
    // 4) dt slice -> bf16
    cvt_dt_k<<<(NROWS * DTRANK) / 256, 256, 0, stream>>>(xdbl, dtb);
    // 5) delta = softplus(dt @ dt_proj^T + b)  [8192,2048] f32  (fast softplus)
    gemm_nt<2><<<dim3(NROWS / 128, DI / 128), 256, 0, stream>>>(dtb, wdt, dlt, dt_proj_b, NROWS, DI, DTRANK);
    // 6) selective scan, two-pass chunked (S=4): local scans -> fixup -> full scan
    scan_seg1<<<3 * 512, 256, 0, stream>>>(dlt, xab, xdbl, A_log, hfin, Pst);
    scan_fix<<<CHTOT / 256, 256, 0, stream>>>(hfin, Pst, hin);
    scan_k2<<<4 * 512, 256, 0, stream>>>(dlt, xab, xdbl, xzb, A_log, Dv, hin, yb);
    // 7) out = y @ out_proj^T  [8192,1024] f32
    gemm_nt<1><<<dim3(NROWS / 128, DM / 128), 256, 0, stream>>>(yb, wout, out, nullptr, NROWS, DM, DI);
}